// Round 3
// baseline (235.026 us; speedup 1.0000x reference)
//
#include <hip/hip_runtime.h>
#include <hip/hip_bf16.h>

#define NF 512
#define HG 256

typedef __attribute__((ext_vector_type(4))) float  f32x4;
typedef __attribute__((ext_vector_type(8))) __bf16 bf16x8;
typedef __attribute__((ext_vector_type(8))) short  s16x8;

static __device__ __forceinline__ unsigned short f2bf(float x) {
    // round-to-nearest-even f32 -> bf16 (finite inputs only)
    unsigned int u = __float_as_uint(x);
    u = (u + 0x7fffu + ((u >> 16) & 1u)) >> 16;
    return (unsigned short)u;
}

// ---------------------------------------------------------------------------
// K1: a = x @ W1[:256], b = x @ W1[256:512]  (f32), plus cc = q @ W1[512:] + b1
//     and zero emb. 128 blocks of 4 rows + 1 special block.
// ---------------------------------------------------------------------------
__global__ __launch_bounds__(256) void prep_ab(
    const float* __restrict__ x, const float* __restrict__ q,
    const float* __restrict__ gW1, const float* __restrict__ gb1,
    float* __restrict__ a, float* __restrict__ b,
    float* __restrict__ cc, float* __restrict__ emb)
{
    const int t = threadIdx.x;
    const int bid = blockIdx.x;
    if (bid == 128) {
        float acc = gb1[t];
        #pragma unroll 8
        for (int d = 0; d < 256; ++d) acc = fmaf(q[d], gW1[(512 + d) * 256 + t], acc);
        cc[t] = acc;
        emb[t] = 0.f;
        return;
    }
    __shared__ float xs[4][256];
    const int r0 = bid * 4;
    #pragma unroll
    for (int r = 0; r < 4; ++r) xs[r][t] = x[(r0 + r) * 256 + t];
    __syncthreads();
    float aa[4] = {0.f, 0.f, 0.f, 0.f}, bb[4] = {0.f, 0.f, 0.f, 0.f};
    #pragma unroll 4
    for (int d = 0; d < 256; ++d) {
        const float wa = gW1[d * 256 + t];
        const float wb = gW1[(256 + d) * 256 + t];
        #pragma unroll
        for (int r = 0; r < 4; ++r) {
            aa[r] = fmaf(xs[r][d], wa, aa[r]);
            bb[r] = fmaf(xs[r][d], wb, bb[r]);
        }
    }
    #pragma unroll
    for (int r = 0; r < 4; ++r) {
        a[(r0 + r) * 256 + t] = aa[r];
        b[(r0 + r) * 256 + t] = bb[r];
    }
}

// ---------------------------------------------------------------------------
// K2: w2t/w3t[n][k] = bf16(W[k][n]) via LDS tile transpose (coalesced both
// ways). 32 blocks: 16 tiles of 64x64 per weight matrix.
// ---------------------------------------------------------------------------
__global__ __launch_bounds__(256) void prep_wt(
    const float* __restrict__ gW2, const float* __restrict__ gW3,
    unsigned short* __restrict__ w2t, unsigned short* __restrict__ w3t)
{
    __shared__ unsigned short tile[64][65];
    const int bid = blockIdx.x;
    const float* src = (bid < 16) ? gW2 : gW3;
    unsigned short* dst = (bid < 16) ? w2t : w3t;
    const int b = bid & 15;
    const int br = (b >> 2) * 64;   // k-block in src
    const int bc = (b & 3) * 64;    // n-block in src
    const int t = threadIdx.x;
    const int tr = t >> 6;          // 0..3
    const int tc = t & 63;
    #pragma unroll
    for (int rr = 0; rr < 16; ++rr) {
        const int r = tr * 16 + rr;   // local k
        tile[r][tc] = f2bf(src[(br + r) * 256 + bc + tc]);
    }
    __syncthreads();
    #pragma unroll
    for (int rr = 0; rr < 16; ++rr) {
        const int r = tr * 16 + rr;   // local n
        dst[(bc + r) * 256 + br + tc] = tile[tc][r];
    }
}

// ---------------------------------------------------------------------------
// K3: main fused pair-MLP. One block per j (512 blocks, 8 waves).
// Per 32-i tile: h1=relu(a_i+b_j+cc) -> LDS(bf16, xor-swizzled);
// layer2/layer3 via mfma_f32_16x16x32_bf16 with register-resident W2t/W3t;
// relu colsums accumulated and atomically added into emb at block end.
// ---------------------------------------------------------------------------
__global__ __launch_bounds__(512, 2) void rn_main(
    const float* __restrict__ ga, const float* __restrict__ gb,
    const float* __restrict__ cc,
    const unsigned short* __restrict__ w2t, const unsigned short* __restrict__ w3t,
    const float* __restrict__ gb2, const float* __restrict__ gb3,
    float* __restrict__ emb)
{
    __shared__ float bc_s[256];
    __shared__ unsigned short h1[32 * 256];
    __shared__ unsigned short h2[32 * 256];

    const int t = threadIdx.x;
    const int j = blockIdx.x;
    const int lane = t & 63;
    const int wave = t >> 6;           // 0..7
    const int l16 = lane & 15;
    const int lk = lane >> 4;          // 0..3 (k-group of 8)
    const int wcol = wave * 32;        // this wave's 32-col slice

    if (t < 256) bc_s[t] = gb[j * 256 + t] + cc[t];

    // register-resident B fragments (bf16), both layers
    bf16x8 B2[2][8], B3[2][8];
    float bias2[2], bias3[2];
    #pragma unroll
    for (int ns = 0; ns < 2; ++ns) {
        const int col = wcol + ns * 16 + l16;
        bias2[ns] = gb2[col];
        bias3[ns] = gb3[col];
        #pragma unroll
        for (int ks = 0; ks < 8; ++ks) {
            const int koff = ks * 32 + lk * 8;
            B2[ns][ks] = *reinterpret_cast<const bf16x8*>(w2t + col * 256 + koff);
            B3[ns][ks] = *reinterpret_cast<const bf16x8*>(w3t + col * 256 + koff);
        }
    }
    float colsum[2] = {0.f, 0.f};
    __syncthreads();   // bc_s ready

    for (int it = 0; it < 16; ++it) {
        const int i0 = it * 32;
        // ---- h1 = relu(a_i + bc) -> bf16 LDS (swizzled) ----
        #pragma unroll
        for (int r = 0; r < 2; ++r) {
            const int idx = t + r * 512;        // 0..1023
            const int m = idx >> 5;             // 0..31
            const int k0 = (idx & 31) << 3;     // 0..248
            const f32x4 a0 = *reinterpret_cast<const f32x4*>(ga + (i0 + m) * 256 + k0);
            const f32x4 a1 = *reinterpret_cast<const f32x4*>(ga + (i0 + m) * 256 + k0 + 4);
            const f32x4 c0 = *reinterpret_cast<const f32x4*>(bc_s + k0);
            const f32x4 c1 = *reinterpret_cast<const f32x4*>(bc_s + k0 + 4);
            s16x8 pk;
            #pragma unroll
            for (int e = 0; e < 4; ++e) {
                float v0 = a0[e] + c0[e]; v0 = v0 > 0.f ? v0 : 0.f;
                float v1 = a1[e] + c1[e]; v1 = v1 > 0.f ? v1 : 0.f;
                pk[e]     = (short)f2bf(v0);
                pk[e + 4] = (short)f2bf(v1);
            }
            *reinterpret_cast<s16x8*>(&h1[(m * 256 + k0) ^ ((m & 7) << 3)]) = pk;
        }
        __syncthreads();   // h1 ready

        // ---- layer 2: h2 = relu(h1 @ W2 + b2) ----
        #pragma unroll
        for (int ms = 0; ms < 2; ++ms) {
            const int row = ms * 16 + l16;
            bf16x8 A[8];
            #pragma unroll
            for (int ks = 0; ks < 8; ++ks) {
                const int koff = ks * 32 + lk * 8;
                A[ks] = *reinterpret_cast<const bf16x8*>(&h1[(row * 256 + koff) ^ ((row & 7) << 3)]);
            }
            #pragma unroll
            for (int ns = 0; ns < 2; ++ns) {
                f32x4 acc = {0.f, 0.f, 0.f, 0.f};
                #pragma unroll
                for (int ks = 0; ks < 8; ++ks)
                    acc = __builtin_amdgcn_mfma_f32_16x16x32_bf16(A[ks], B2[ns][ks], acc, 0, 0, 0);
                const int ccol = wcol + ns * 16 + l16;
                #pragma unroll
                for (int reg = 0; reg < 4; ++reg) {
                    float v = acc[reg] + bias2[ns];
                    v = v > 0.f ? v : 0.f;
                    const int rr = ms * 16 + lk * 4 + reg;   // C row = (lane>>4)*4+reg
                    h2[(rr * 256 + ccol) ^ ((rr & 7) << 3)] = f2bf(v);
                }
            }
        }
        __syncthreads();   // h2 ready (h1 rewrite is gated by next-iter barrier)

        // ---- layer 3: rel = relu(h2 @ W3 + b3); colsum += rel ----
        #pragma unroll
        for (int ms = 0; ms < 2; ++ms) {
            const int row = ms * 16 + l16;
            bf16x8 A[8];
            #pragma unroll
            for (int ks = 0; ks < 8; ++ks) {
                const int koff = ks * 32 + lk * 8;
                A[ks] = *reinterpret_cast<const bf16x8*>(&h2[(row * 256 + koff) ^ ((row & 7) << 3)]);
            }
            #pragma unroll
            for (int ns = 0; ns < 2; ++ns) {
                f32x4 acc = {0.f, 0.f, 0.f, 0.f};
                #pragma unroll
                for (int ks = 0; ks < 8; ++ks)
                    acc = __builtin_amdgcn_mfma_f32_16x16x32_bf16(A[ks], B3[ns][ks], acc, 0, 0, 0);
                float s = 0.f;
                #pragma unroll
                for (int reg = 0; reg < 4; ++reg) {
                    float v = acc[reg] + bias3[ns];
                    s += (v > 0.f ? v : 0.f);
                }
                colsum[ns] += s;
            }
        }
    }

    // ---- reduce colsums across the 4 row-groups, one atomic per col ----
    #pragma unroll
    for (int ns = 0; ns < 2; ++ns) {
        float v = colsum[ns];
        v += __shfl_xor(v, 16, 64);
        v += __shfl_xor(v, 32, 64);
        if (lane < 16) atomicAdd(&emb[wcol + ns * 16 + l16], v);
    }
}

// ---------------------------------------------------------------------------
// K4: f-MLP on emb (tiny). One block.
// ---------------------------------------------------------------------------
__global__ __launch_bounds__(512) void rn_final(
    const float* __restrict__ emb,
    const float* __restrict__ fW1, const float* __restrict__ fb1,
    const float* __restrict__ fW2, const float* __restrict__ fb2,
    const float* __restrict__ fW3, const float* __restrict__ fb3,
    float* __restrict__ out)
{
    __shared__ float e_s[256], y1_s[256], y2_s[512];
    const int t = threadIdx.x;
    if (t < 256) e_s[t] = emb[t];
    __syncthreads();
    if (t < 256) {
        float acc = fb1[t];
        #pragma unroll 8
        for (int k = 0; k < 256; ++k) acc = fmaf(e_s[k], fW1[k * 256 + t], acc);
        y1_s[t] = acc > 0.f ? acc : 0.f;
    }
    __syncthreads();
    {
        float acc = fb2[t];
        #pragma unroll 8
        for (int k = 0; k < 256; ++k) acc = fmaf(y1_s[k], fW2[k * 512 + t], acc);
        y2_s[t] = acc > 0.f ? acc : 0.f;
    }
    __syncthreads();
    if (t < 159) {
        float acc = fb3[t];
        #pragma unroll 8
        for (int k = 0; k < 512; ++k) acc = fmaf(y2_s[k], fW3[k * 159 + t], acc);
        out[t] = acc;
    }
}

// ---------------------------------------------------------------------------
extern "C" void kernel_launch(void* const* d_in, const int* in_sizes, int n_in,
                              void* d_out, int out_size, void* d_ws, size_t ws_size,
                              hipStream_t stream)
{
    const float* x   = (const float*)d_in[0];
    const float* q   = (const float*)d_in[1];
    const float* gW1 = (const float*)d_in[2];
    const float* gb1 = (const float*)d_in[3];
    const float* gW2 = (const float*)d_in[4];
    const float* gb2 = (const float*)d_in[5];
    const float* gW3 = (const float*)d_in[6];
    const float* gb3 = (const float*)d_in[7];
    const float* fW1 = (const float*)d_in[8];
    const float* fb1 = (const float*)d_in[9];
    const float* fW2 = (const float*)d_in[10];
    const float* fb2 = (const float*)d_in[11];
    const float* fW3 = (const float*)d_in[12];
    const float* fb3 = (const float*)d_in[13];
    float* out = (float*)d_out;

    char* ws = (char*)d_ws;
    float* a_  = (float*)(ws);                                  // 512*256 f32 = 512KB
    float* b_  = (float*)(ws + 512 * 1024);                     // 512KB
    float* cc  = (float*)(ws + 1024 * 1024);                    // 1KB
    float* emb = (float*)(ws + 1024 * 1024 + 1024);             // 1KB
    unsigned short* w2t = (unsigned short*)(ws + 1024 * 1024 + 2048);              // 128KB
    unsigned short* w3t = (unsigned short*)(ws + 1024 * 1024 + 2048 + 128 * 1024); // 128KB

    prep_ab<<<129, 256, 0, stream>>>(x, q, gW1, gb1, a_, b_, cc, emb);
    prep_wt<<<32, 256, 0, stream>>>(gW2, gW3, w2t, w3t);
    rn_main<<<512, 512, 0, stream>>>(a_, b_, cc, w2t, w3t, gb2, gb3, emb);
    rn_final<<<1, 512, 0, stream>>>(emb, fW1, fb1, fW2, fb2, fW3, fb3, out);
}

// Round 4
// 219.199 us; speedup vs baseline: 1.0722x; 1.0722x over previous
//
#include <hip/hip_runtime.h>
#include <hip/hip_bf16.h>

typedef __attribute__((ext_vector_type(4))) float  f32x4;
typedef __attribute__((ext_vector_type(8))) __bf16 bf16x8;

static __device__ __forceinline__ unsigned short bfbits(float x) {
    return __builtin_bit_cast(unsigned short, (__bf16)x);
}

// ---------------------------------------------------------------------------
// K1 (fused prep): blocks 0..127: a,b = x @ W1 halves; block 128: cc + emb=0;
// blocks 129..160: bf16 transpose of W2/W3.
// ---------------------------------------------------------------------------
__global__ __launch_bounds__(256) void prep_all(
    const float* __restrict__ x, const float* __restrict__ q,
    const float* __restrict__ gW1, const float* __restrict__ gb1,
    const float* __restrict__ gW2, const float* __restrict__ gW3,
    float* __restrict__ a, float* __restrict__ b,
    float* __restrict__ cc, float* __restrict__ emb,
    unsigned short* __restrict__ w2t, unsigned short* __restrict__ w3t)
{
    const int t = threadIdx.x;
    const int bid = blockIdx.x;
    if (bid < 128) {
        __shared__ float xs[4][256];
        const int r0 = bid * 4;
        #pragma unroll
        for (int r = 0; r < 4; ++r) xs[r][t] = x[(r0 + r) * 256 + t];
        __syncthreads();
        float aa[4] = {0.f, 0.f, 0.f, 0.f}, bb[4] = {0.f, 0.f, 0.f, 0.f};
        #pragma unroll 4
        for (int d = 0; d < 256; ++d) {
            const float wa = gW1[d * 256 + t];
            const float wb = gW1[(256 + d) * 256 + t];
            #pragma unroll
            for (int r = 0; r < 4; ++r) {
                aa[r] = fmaf(xs[r][d], wa, aa[r]);
                bb[r] = fmaf(xs[r][d], wb, bb[r]);
            }
        }
        #pragma unroll
        for (int r = 0; r < 4; ++r) {
            a[(r0 + r) * 256 + t] = aa[r];
            b[(r0 + r) * 256 + t] = bb[r];
        }
    } else if (bid == 128) {
        float acc = gb1[t];
        #pragma unroll 8
        for (int d = 0; d < 256; ++d) acc = fmaf(q[d], gW1[(512 + d) * 256 + t], acc);
        cc[t] = acc;
        emb[t] = 0.f;
    } else {
        __shared__ unsigned short tile[64][65];
        const int bb_ = bid - 129;                 // 0..31
        const float* src = (bb_ < 16) ? gW2 : gW3;
        unsigned short* dst = (bb_ < 16) ? w2t : w3t;
        const int bidx = bb_ & 15;
        const int br = (bidx >> 2) * 64;   // k-block in src
        const int bc = (bidx & 3) * 64;    // n-block in src
        const int tr = t >> 6;             // 0..3
        const int tc = t & 63;
        #pragma unroll
        for (int rr = 0; rr < 16; ++rr) {
            const int r = tr * 16 + rr;    // local k
            tile[r][tc] = bfbits(src[(br + r) * 256 + bc + tc]);
        }
        __syncthreads();
        #pragma unroll
        for (int rr = 0; rr < 16; ++rr) {
            const int r = tr * 16 + rr;    // local n
            dst[(bc + r) * 256 + br + tc] = tile[tc][r];
        }
    }
}

// ---------------------------------------------------------------------------
// K2: main fused pair-MLP. One block per j (512 blocks, 8 waves), M=64 tiles.
// Per tile: Phase A = L2 MFMA (h1->h2); barrier; Phase B = h1-gen(next tile)
// interleaved with L3 MFMA (h2->colsum); barrier. bc held in registers.
// ---------------------------------------------------------------------------
__global__ __launch_bounds__(512, 2) void rn_main(
    const float* __restrict__ ga, const float* __restrict__ gb,
    const float* __restrict__ cc,
    const unsigned short* __restrict__ w2t, const unsigned short* __restrict__ w3t,
    const float* __restrict__ gb2, const float* __restrict__ gb3,
    float* __restrict__ emb)
{
    __shared__ __bf16 h1[64 * 256];   // 32KB
    __shared__ __bf16 h2[64 * 256];   // 32KB

    const int t = threadIdx.x;
    const int j = blockIdx.x;
    const int lane = t & 63;
    const int wave = t >> 6;           // 0..7
    const int l16 = lane & 15;
    const int lk = lane >> 4;          // 0..3 (k-group of 8)
    const int wcol = wave * 32;        // this wave's 32-col slice

    // ---- bc = b[j] + cc, in registers (k0 = this thread's h1-gen k-slice) ----
    const int k0 = (t & 31) << 3;
    f32x4 bc0, bc1;
    {
        const f32x4 g0 = *reinterpret_cast<const f32x4*>(gb + j * 256 + k0);
        const f32x4 g1 = *reinterpret_cast<const f32x4*>(gb + j * 256 + k0 + 4);
        const f32x4 c0 = *reinterpret_cast<const f32x4*>(cc + k0);
        const f32x4 c1 = *reinterpret_cast<const f32x4*>(cc + k0 + 4);
        #pragma unroll
        for (int e = 0; e < 4; ++e) { bc0[e] = g0[e] + c0[e]; bc1[e] = g1[e] + c1[e]; }
    }

    // ---- register/AGPR-resident B fragments (bf16), both layers ----
    bf16x8 B2[2][8], B3[2][8];
    float bias2[2], bias3[2];
    #pragma unroll
    for (int ns = 0; ns < 2; ++ns) {
        const int col = wcol + ns * 16 + l16;
        bias2[ns] = gb2[col];
        bias3[ns] = gb3[col];
        #pragma unroll
        for (int ks = 0; ks < 8; ++ks) {
            const int koff = ks * 32 + lk * 8;
            B2[ns][ks] = *reinterpret_cast<const bf16x8*>(w2t + col * 256 + koff);
            B3[ns][ks] = *reinterpret_cast<const bf16x8*>(w3t + col * 256 + koff);
        }
    }
    float colsum[2] = {0.f, 0.f};

    // h1 generator for a 64-row tile starting at row I0 (4 passes / thread)
    #define GEN_H1(I0)                                                              \
    {                                                                               \
        _Pragma("unroll")                                                           \
        for (int r = 0; r < 4; ++r) {                                               \
            const int m = (t >> 5) + r * 16;                                        \
            const f32x4 a0 = *reinterpret_cast<const f32x4*>(ga + ((I0) + m) * 256 + k0);     \
            const f32x4 a1 = *reinterpret_cast<const f32x4*>(ga + ((I0) + m) * 256 + k0 + 4); \
            bf16x8 pk;                                                              \
            _Pragma("unroll")                                                       \
            for (int e = 0; e < 4; ++e) {                                           \
                pk[e]     = (__bf16)fmaxf(a0[e] + bc0[e], 0.f);                     \
                pk[e + 4] = (__bf16)fmaxf(a1[e] + bc1[e], 0.f);                     \
            }                                                                       \
            *reinterpret_cast<bf16x8*>(&h1[(m * 256 + k0) ^ ((m & 7) << 3)]) = pk;  \
        }                                                                           \
    }

    GEN_H1(0);
    __syncthreads();

    for (int it = 0; it < 8; ++it) {
        // ---- Phase A: layer 2, h1 -> h2 ----
        #pragma unroll
        for (int ms = 0; ms < 4; ++ms) {
            const int row = ms * 16 + l16;
            bf16x8 A[8];
            #pragma unroll
            for (int ks = 0; ks < 8; ++ks) {
                const int koff = ks * 32 + lk * 8;
                A[ks] = *reinterpret_cast<const bf16x8*>(&h1[(row * 256 + koff) ^ ((row & 7) << 3)]);
            }
            #pragma unroll
            for (int ns = 0; ns < 2; ++ns) {
                f32x4 acc = {0.f, 0.f, 0.f, 0.f};
                #pragma unroll
                for (int ks = 0; ks < 8; ++ks)
                    acc = __builtin_amdgcn_mfma_f32_16x16x32_bf16(A[ks], B2[ns][ks], acc, 0, 0, 0);
                const int ccol = wcol + ns * 16 + l16;
                #pragma unroll
                for (int reg = 0; reg < 4; ++reg) {
                    const float v = fmaxf(acc[reg] + bias2[ns], 0.f);
                    const int rr = ms * 16 + lk * 4 + reg;   // C row = (lane>>4)*4+reg
                    h2[(rr * 256 + ccol) ^ ((rr & 7) << 3)] = (__bf16)v;
                }
            }
        }
        __syncthreads();   // h2 ready; all h1 reads done

        // ---- Phase B: h1-gen for next tile (global+VALU) || layer 3 (MFMA) ----
        if (it < 7) GEN_H1((it + 1) * 64);
        #pragma unroll
        for (int ms = 0; ms < 4; ++ms) {
            const int row = ms * 16 + l16;
            bf16x8 A[8];
            #pragma unroll
            for (int ks = 0; ks < 8; ++ks) {
                const int koff = ks * 32 + lk * 8;
                A[ks] = *reinterpret_cast<const bf16x8*>(&h2[(row * 256 + koff) ^ ((row & 7) << 3)]);
            }
            #pragma unroll
            for (int ns = 0; ns < 2; ++ns) {
                f32x4 acc = {0.f, 0.f, 0.f, 0.f};
                #pragma unroll
                for (int ks = 0; ks < 8; ++ks)
                    acc = __builtin_amdgcn_mfma_f32_16x16x32_bf16(A[ks], B3[ns][ks], acc, 0, 0, 0);
                float s = 0.f;
                #pragma unroll
                for (int reg = 0; reg < 4; ++reg)
                    s += fmaxf(acc[reg] + bias3[ns], 0.f);
                colsum[ns] += s;
            }
        }
        __syncthreads();   // h2 consumed + h1(next) ready
    }

    // ---- reduce colsums across the 4 row-groups, one atomic per col ----
    #pragma unroll
    for (int ns = 0; ns < 2; ++ns) {
        float v = colsum[ns];
        v += __shfl_xor(v, 16, 64);
        v += __shfl_xor(v, 32, 64);
        if (lane < 16) atomicAdd(&emb[wcol + ns * 16 + l16], v);
    }
    #undef GEN_H1
}

// ---------------------------------------------------------------------------
// K3: f-MLP on emb. One block, 1024 threads, k-split per layer + LDS reduce.
// ---------------------------------------------------------------------------
__global__ __launch_bounds__(1024) void rn_final(
    const float* __restrict__ emb,
    const float* __restrict__ fW1, const float* __restrict__ fb1,
    const float* __restrict__ fW2, const float* __restrict__ fb2,
    const float* __restrict__ fW3, const float* __restrict__ fb3,
    float* __restrict__ out)
{
    __shared__ float e_s[256];
    __shared__ float red[1024];
    __shared__ float y1[256];
    __shared__ float y2[512];
    const int t = threadIdx.x;
    if (t < 256) e_s[t] = emb[t];
    __syncthreads();
    // f1: 256 cols x 4-way k-split (64 each)
    {
        const int col = t & 255, ks = t >> 8;
        float acc = 0.f;
        #pragma unroll 8
        for (int k = ks * 64; k < ks * 64 + 64; ++k) acc = fmaf(e_s[k], fW1[k * 256 + col], acc);
        red[ks * 256 + col] = acc;
    }
    __syncthreads();
    if (t < 256)
        y1[t] = fmaxf(red[t] + red[256 + t] + red[512 + t] + red[768 + t] + fb1[t], 0.f);
    __syncthreads();
    // f2: 512 cols x 2-way k-split (128 each)
    {
        const int col = t & 511, ks = t >> 9;
        float acc = 0.f;
        #pragma unroll 8
        for (int k = ks * 128; k < ks * 128 + 128; ++k) acc = fmaf(y1[k], fW2[k * 512 + col], acc);
        red[ks * 512 + col] = acc;
    }
    __syncthreads();
    if (t < 512) y2[t] = fmaxf(red[t] + red[512 + t] + fb2[t], 0.f);
    __syncthreads();
    // f3: 159 cols x 4-way k-split (128 each); cols padded to 256
    {
        const int col = t & 255, ks = t >> 8;
        if (col < 159) {
            float acc = 0.f;
            #pragma unroll 8
            for (int k = ks * 128; k < ks * 128 + 128; ++k) acc = fmaf(y2[k], fW3[k * 159 + col], acc);
            red[ks * 256 + col] = acc;
        }
    }
    __syncthreads();
    if (t < 159)
        out[t] = red[t] + red[256 + t] + red[512 + t] + red[768 + t] + fb3[t];
}

// ---------------------------------------------------------------------------
extern "C" void kernel_launch(void* const* d_in, const int* in_sizes, int n_in,
                              void* d_out, int out_size, void* d_ws, size_t ws_size,
                              hipStream_t stream)
{
    const float* x   = (const float*)d_in[0];
    const float* q   = (const float*)d_in[1];
    const float* gW1 = (const float*)d_in[2];
    const float* gb1 = (const float*)d_in[3];
    const float* gW2 = (const float*)d_in[4];
    const float* gb2 = (const float*)d_in[5];
    const float* gW3 = (const float*)d_in[6];
    const float* gb3 = (const float*)d_in[7];
    const float* fW1 = (const float*)d_in[8];
    const float* fb1 = (const float*)d_in[9];
    const float* fW2 = (const float*)d_in[10];
    const float* fb2 = (const float*)d_in[11];
    const float* fW3 = (const float*)d_in[12];
    const float* fb3 = (const float*)d_in[13];
    float* out = (float*)d_out;

    char* ws = (char*)d_ws;
    float* a_  = (float*)(ws);                                  // 512*256 f32 = 512KB
    float* b_  = (float*)(ws + 512 * 1024);                     // 512KB
    float* cc  = (float*)(ws + 1024 * 1024);                    // 1KB
    float* emb = (float*)(ws + 1024 * 1024 + 1024);             // 1KB
    unsigned short* w2t = (unsigned short*)(ws + 1024 * 1024 + 2048);              // 128KB
    unsigned short* w3t = (unsigned short*)(ws + 1024 * 1024 + 2048 + 128 * 1024); // 128KB

    prep_all<<<161, 256, 0, stream>>>(x, q, gW1, gb1, gW2, gW3, a_, b_, cc, emb, w2t, w3t);
    rn_main<<<512, 512, 0, stream>>>(a_, b_, cc, w2t, w3t, gb2, gb3, emb);
    rn_final<<<1, 1024, 0, stream>>>(emb, fW1, fb1, fW2, fb2, fW3, fb3, out);
}